// Round 3
// baseline (194677.930 us; speedup 1.0000x reference)
//
#include <hip/hip_runtime.h>

// PEPS 10x10 boundary-MPS contraction, D=8, Dc=64, 2 sweeps, fp32.
// Host-orchestrated graph of ~1490 small kernels. All shapes are static
// (data-independent), so the schedule is identical every call (graph-safe).
//
// Conventions (matching the JAX reference):
//   mps site  m: (d, p, r)          row-major
//   mpo site  w: (l, w, p, q)       row-major  (p = up/in, q = down/out)
//   result    A: (a, q, b)          row-major
//   left env  L: (d, l, a)          row-major
//   right env R: (r, w, b)          row-major
// QR: Q_k = orthonormalization (MGS2) of the first KK columns; R = Q_k^T A.
// Gauge-invariance of the final scalar makes the QR basis convention free
// (MGS2 Q == Householder Q up to an orthogonal rotation within the kept
// subspace; the rotation cancels between result[i] and carry/env usage).
// Sweep neighbor C-updates in the reference are dead code and are elided.

#define TINYF 1e-30f

__global__ void k_init(float* u){ u[0] = 1.0f; }

// Build all 100 MPO tensors: t = tensors[row,col,spin,:up,:dn,:lf,:rt] -> (l,w,p,q)
__global__ void k_mpo(const float* __restrict__ T, const int* __restrict__ spins,
                      float* __restrict__ mpo){
  int s = blockIdx.x; int row = s / 10, col = s % 10;
  int up = (row == 0) ? 1 : 8, dn = (row == 9) ? 1 : 8;
  int lf = (col == 0) ? 1 : 8, rt = (col == 9) ? 1 : 8;
  int spin = spins[s];
  const float* src = T + (size_t)(s * 2 + spin) * 4096; // strides: up=512, dn=64, lf=8, rt=1
  float* dst = mpo + (size_t)s * 4096;                  // (l, w, p, q) packed
  int n = lf * rt * up * dn;
  for (int i = threadIdx.x; i < n; i += blockDim.x){
    int q = i % dn, t1 = i / dn, p = t1 % up, t2 = t1 / up, w = t2 % rt, l = t2 / rt;
    dst[i] = src[p * 512 + q * 64 + l * 8 + w];
  }
}

// theta[k,q,r,w] = sum_{d,l,p} carry[k,d,l] m[d,p,r] w[l,w,p,q]
// out as matrix: out[(k*Qd+q)*(rm*Ww) + r*Ww + w_]
__global__ __launch_bounds__(256) void k_init_theta(
    const float* __restrict__ carry, const float* __restrict__ m,
    const float* __restrict__ w, float* __restrict__ out,
    int kdim, int dm, int lw, int P, int rm, int Ww, int Qd){
  int k = blockIdx.x;
  __shared__ float sC[512];    // (dm, lw)
  __shared__ float sT1[4096];  // (p*rm + r)*lw + l
  __shared__ float sW[4096];
  for (int i = threadIdx.x; i < dm * lw; i += blockDim.x) sC[i] = carry[(size_t)k * dm * lw + i];
  for (int i = threadIdx.x; i < lw * Ww * P * Qd; i += blockDim.x) sW[i] = w[i];
  __syncthreads();
  // stage 1: per-thread (p,r) pair, global operand hoisted per d
  for (int j = threadIdx.x; j < P * rm; j += blockDim.x){
    int r = j % rm, p = j / rm;
    float acc[8];
    #pragma unroll
    for (int l = 0; l < 8; ++l) acc[l] = 0.f;
    for (int d = 0; d < dm; ++d){
      float mv = m[((size_t)d * P + p) * rm + r];
      #pragma unroll
      for (int l = 0; l < 8; ++l) if (l < lw) acc[l] += mv * sC[d * lw + l];
    }
    float* dst = sT1 + (size_t)j * lw;
    for (int l = 0; l < lw; ++l) dst[l] = acc[l];
  }
  __syncthreads();
  int n2 = Qd * rm * Ww;
  int ldo = rm * Ww;
  for (int i = threadIdx.x; i < n2; i += blockDim.x){
    int w_ = i % Ww, t = i / Ww, r = t % rm, q = t / rm;
    float acc = 0.f;
    for (int l = 0; l < lw; ++l)
      for (int p = 0; p < P; ++p)
        acc += sT1[(p * rm + r) * lw + l] * sW[((l * Ww + w_) * P + p) * Qd + q];
    out[(size_t)(k * Qd + q) * ldo + r * Ww + w_] = acc;
  }
}

// Orthonormalize first KK columns of A (M rows), strided access, MGS2.
// A(row,col) at A[row*ars + col*acs]; Q(row,col) at Q[row*qrs + col*qcs].
// 1024 threads = 64 groups x 16 lanes; column stride padded (+4 floats) so
// group bank offsets are {4g mod 32} -> <=2-way conflict (free, m136).
__global__ __launch_bounds__(1024) void k_panel(
    const float* __restrict__ A, float* __restrict__ Q,
    int M, int KK, int ars, int acs, int qrs, int qcs){
  __shared__ __align__(16) float ls[64 * 516];   // 129 KiB (gfx950 LDS = 160 KiB)
  __shared__ float nrm[64];
  int Mp = M + 4;                                 // (M+4)*4B is 16B-multiple when 4|M
  int tot = KK * M;
  if (acs == 1){
    for (int i = threadIdx.x; i < tot; i += blockDim.x){
      int c = i % KK, r = i / KK;                  // c-fast: coalesced A read
      ls[c * Mp + r] = A[(size_t)r * ars + c];
    }
  } else {
    for (int i = threadIdx.x; i < tot; i += blockDim.x){
      int r = i % M, c = i / M;                    // r-fast: coalesced A read
      ls[c * Mp + r] = A[(size_t)r * ars + (size_t)c * acs];
    }
  }
  __syncthreads();
  int g = threadIdx.x >> 4, lane = threadIdx.x & 15;
  bool vec4 = ((M & 3) == 0);
  int M4 = M >> 2;
  for (int pass = 0; pass < 2; ++pass){
    if (g < KK){
      const float* col = ls + g * Mp;
      float s = 0.f;
      if (vec4){
        const float4* c4 = (const float4*)col;
        for (int r = lane; r < M4; r += 16){ float4 v = c4[r]; s += v.x*v.x + v.y*v.y + v.z*v.z + v.w*v.w; }
      } else {
        for (int r = lane; r < M; r += 16) s += col[r] * col[r];
      }
      s += __shfl_xor(s,1); s += __shfl_xor(s,2); s += __shfl_xor(s,4); s += __shfl_xor(s,8);
      if (lane == 0) nrm[g] = s;
    }
    __syncthreads();
    for (int j = 0; j < KK - 1; ++j){
      int jj = j + 1 + g;
      if (jj < KK){
        const float* cj = ls + j * Mp;
        float* cx = ls + jj * Mp;
        float d = 0.f;
        if (vec4){
          const float4* cj4 = (const float4*)cj; const float4* cx4 = (const float4*)cx;
          for (int r = lane; r < M4; r += 16){
            float4 a = cj4[r], b = cx4[r];
            d += a.x*b.x + a.y*b.y + a.z*b.z + a.w*b.w;
          }
        } else {
          for (int r = lane; r < M; r += 16) d += cj[r] * cx[r];
        }
        d += __shfl_xor(d,1); d += __shfl_xor(d,2); d += __shfl_xor(d,4); d += __shfl_xor(d,8);
        float coef = d / fmaxf(nrm[j], TINYF);
        float ns = 0.f;
        if (vec4){
          const float4* cj4 = (const float4*)cj; float4* cx4 = (float4*)cx;
          for (int r = lane; r < M4; r += 16){
            float4 a = cj4[r], b = cx4[r];
            b.x -= coef*a.x; b.y -= coef*a.y; b.z -= coef*a.z; b.w -= coef*a.w;
            cx4[r] = b;
            ns += b.x*b.x + b.y*b.y + b.z*b.z + b.w*b.w;
          }
        } else {
          for (int r = lane; r < M; r += 16){ float v = cx[r] - coef * cj[r]; cx[r] = v; ns += v * v; }
        }
        ns += __shfl_xor(ns,1); ns += __shfl_xor(ns,2); ns += __shfl_xor(ns,4); ns += __shfl_xor(ns,8);
        if (lane == 0) nrm[jj] = ns;
      }
      __syncthreads();
    }
  }
  if (qcs == 1){
    for (int i = threadIdx.x; i < tot; i += blockDim.x){
      int c = i % KK, r = i / KK;                  // c-fast: coalesced Q write
      Q[(size_t)r * qrs + c] = ls[c * Mp + r] * rsqrtf(fmaxf(nrm[c], TINYF));
    }
  } else {
    for (int i = threadIdx.x; i < tot; i += blockDim.x){
      int r = i % M, c = i / M;                    // r-fast: coalesced Q write
      Q[(size_t)r * qrs + (size_t)c * qcs] = ls[c * Mp + r] * rsqrtf(fmaxf(nrm[c], TINYF));
    }
  }
}

// R[c][n] = sum_m Q[m*KK + c] * A[m*ars + n*acs]   (R: KK x N, row-major)
__global__ __launch_bounds__(256) void k_rmat(
    const float* __restrict__ Q, const float* __restrict__ A, float* __restrict__ R,
    int M, int KK, int N, int ars, int acs){
  int idx = blockIdx.x * blockDim.x + threadIdx.x;
  if (idx >= KK * N) return;
  int n = idx % N, c = idx / N;
  float acc = 0.f;
  for (int mm = 0; mm < M; ++mm)
    acc += Q[(size_t)mm * KK + c] * A[(size_t)mm * ars + (size_t)n * acs];
  R[idx] = acc;
}

// optimal[a,q,b] = sum m[d,p,r] L[d,l,a] w[l,w,p,q] R[r,w,b]; one WG per a.
__global__ __launch_bounds__(256) void k_optimal(
    const float* __restrict__ m, const float* __restrict__ L,
    const float* __restrict__ w, const float* __restrict__ Renv, float* __restrict__ out,
    int dm, int P, int rm, int lw, int aL, int Ww, int Qd, int bR){
  int a = blockIdx.x;
  __shared__ float sL[512];    // (dm, lw)
  __shared__ float sT1[4096];  // (p*rm + r)*lw + l
  __shared__ float sT2[4096];  // (r*Ww + w_)*Qd + q
  __shared__ float sW[4096];
  for (int i = threadIdx.x; i < dm * lw; i += blockDim.x){
    int d = i / lw, l = i % lw;
    sL[i] = L[((size_t)d * lw + l) * aL + a];
  }
  for (int i = threadIdx.x; i < lw * Ww * P * Qd; i += blockDim.x) sW[i] = w[i];
  __syncthreads();
  for (int j = threadIdx.x; j < P * rm; j += blockDim.x){
    int r = j % rm, p = j / rm;
    float acc[8];
    #pragma unroll
    for (int l = 0; l < 8; ++l) acc[l] = 0.f;
    for (int d = 0; d < dm; ++d){
      float mv = m[((size_t)d * P + p) * rm + r];
      #pragma unroll
      for (int l = 0; l < 8; ++l) if (l < lw) acc[l] += mv * sL[d * lw + l];
    }
    float* dst = sT1 + (size_t)j * lw;
    for (int l = 0; l < lw; ++l) dst[l] = acc[l];
  }
  __syncthreads();
  for (int i = threadIdx.x; i < rm * Ww * Qd; i += blockDim.x){
    int q = i % Qd, t = i / Qd, w_ = t % Ww, r = t / Ww;
    float acc = 0.f;
    for (int l = 0; l < lw; ++l)
      for (int p = 0; p < P; ++p)
        acc += sT1[(p * rm + r) * lw + l] * sW[((l * Ww + w_) * P + p) * Qd + q];
    sT2[i] = acc;
  }
  __syncthreads();
  int n3 = Qd * bR;
  for (int i = threadIdx.x; i < n3; i += blockDim.x){
    int b = i % bR, q = i / bR;
    float acc = 0.f;
    for (int r = 0; r < rm; ++r)
      for (int w_ = 0; w_ < Ww; ++w_)
        acc += sT2[(r * Ww + w_) * Qd + q] * Renv[((size_t)r * Ww + w_) * bR + b];
    out[((size_t)a * Qd + q) * bR + b] = acc;
  }
}

// Lnew[r,w,b] = sum m[d,p,r] L[d,l,a] w[l,w,p,q] A[a,q,b]; one WG per r.
__global__ __launch_bounds__(256) void k_lenv(
    const float* __restrict__ m, const float* __restrict__ L,
    const float* __restrict__ w, const float* __restrict__ A, float* __restrict__ out,
    int dm, int P, int rm, int lw, int aL, int Ww, int Qd, int KK){
  int r = blockIdx.x;
  __shared__ float sM[512];    // (dm, P)
  __shared__ float sT1[4096];  // (p*lw + l)*aL + a
  __shared__ float sT2[4096];  // (a*Ww + w_)*Qd + q
  __shared__ float sW[4096];
  for (int i = threadIdx.x; i < dm * P; i += blockDim.x){
    int d = i / P, p = i % P;
    sM[i] = m[((size_t)d * P + p) * rm + r];
  }
  for (int i = threadIdx.x; i < lw * Ww * P * Qd; i += blockDim.x) sW[i] = w[i];
  __syncthreads();
  for (int j = threadIdx.x; j < lw * aL; j += blockDim.x){
    int a = j % aL, l = j / aL;
    float acc[8];
    #pragma unroll
    for (int p = 0; p < 8; ++p) acc[p] = 0.f;
    for (int d = 0; d < dm; ++d){
      float Lv = L[((size_t)d * lw + l) * aL + a];
      #pragma unroll
      for (int p = 0; p < 8; ++p) if (p < P) acc[p] += sM[d * P + p] * Lv;
    }
    for (int p = 0; p < P; ++p) sT1[(size_t)p * lw * aL + j] = acc[p];
  }
  __syncthreads();
  for (int i = threadIdx.x; i < aL * Ww * Qd; i += blockDim.x){
    int q = i % Qd, t = i / Qd, w_ = t % Ww, a = t / Ww;
    float acc = 0.f;
    for (int l = 0; l < lw; ++l)
      for (int p = 0; p < P; ++p)
        acc += sT1[(p * lw + l) * aL + a] * sW[((l * Ww + w_) * P + p) * Qd + q];
    sT2[i] = acc;
  }
  __syncthreads();
  int n3 = Ww * KK;
  for (int i = threadIdx.x; i < n3; i += blockDim.x){
    int b = i % KK, w_ = i / KK;
    float acc = 0.f;
    for (int a = 0; a < aL; ++a)
      for (int q = 0; q < Qd; ++q)
        acc += sT2[(a * Ww + w_) * Qd + q] * A[((size_t)a * Qd + q) * KK + b];
    out[((size_t)r * Ww + w_) * KK + b] = acc;
  }
}

// Rnew[d,l,a] = sum B[a,q,b] R[r,w,b] w[l,w,p,q] m[d,p,r]; one WG per a.
__global__ __launch_bounds__(256) void k_renv(
    const float* __restrict__ B, const float* __restrict__ R,
    const float* __restrict__ w, const float* __restrict__ m, float* __restrict__ out,
    int aB, int Qd, int bR, int rm, int Ww, int lw, int P, int dm){
  int a = blockIdx.x;
  __shared__ float sB[512];    // (Qd, bR)
  __shared__ float sT1[4096];  // (q*rm + r)*Ww + w_
  __shared__ float sT2[4096];  // (r*lw + l)*P + p
  __shared__ float sW[4096];
  for (int i = threadIdx.x; i < Qd * bR; i += blockDim.x) sB[i] = B[(size_t)a * Qd * bR + i];
  for (int i = threadIdx.x; i < lw * Ww * P * Qd; i += blockDim.x) sW[i] = w[i];
  __syncthreads();
  for (int j = threadIdx.x; j < rm * Ww; j += blockDim.x){
    float acc[8];
    #pragma unroll
    for (int q = 0; q < 8; ++q) acc[q] = 0.f;
    const float* Rrow = R + (size_t)j * bR;     // j = r*Ww + w_
    for (int b = 0; b < bR; ++b){
      float Rv = Rrow[b];
      #pragma unroll
      for (int q = 0; q < 8; ++q) if (q < Qd) acc[q] += sB[q * bR + b] * Rv;
    }
    for (int q = 0; q < Qd; ++q) sT1[(size_t)q * rm * Ww + j] = acc[q];
  }
  __syncthreads();
  for (int i = threadIdx.x; i < rm * lw * P; i += blockDim.x){
    int p = i % P, t = i / P, l = t % lw, r = t / lw;
    float acc = 0.f;
    for (int q = 0; q < Qd; ++q)
      for (int w_ = 0; w_ < Ww; ++w_)
        acc += sT1[(q * rm + r) * Ww + w_] * sW[((l * Ww + w_) * P + p) * Qd + q];
    sT2[i] = acc;
  }
  __syncthreads();
  for (int i = threadIdx.x; i < dm * lw; i += blockDim.x){
    int l = i % lw, d = i / lw;
    float acc = 0.f;
    for (int r = 0; r < rm; ++r)
      for (int p = 0; p < P; ++p)
        acc += sT2[(r * lw + l) * P + p] * m[((size_t)d * P + p) * rm + r];
    out[((size_t)d * lw + l) * aB + a] = acc;
  }
}

struct FinalArgs { const float* t[10]; int dl[10]; int dr[10]; };

__global__ void k_final(FinalArgs fa, float* __restrict__ out){
  __shared__ float v0[64], v1[64];
  float* cur = v0; float* nxt = v1;
  if (threadIdx.x == 0) cur[0] = 1.0f;
  __syncthreads();
  for (int s = 0; s < 10; ++s){
    const float* T = fa.t[s]; int dl = fa.dl[s], dr = fa.dr[s];
    for (int j = threadIdx.x; j < dr; j += blockDim.x){
      float acc = 0.f;
      for (int i = 0; i < dl; ++i) acc += cur[i] * T[(size_t)i * dr + j];
      nxt[j] = acc;
    }
    __syncthreads();
    float* tmp = cur; cur = nxt; nxt = tmp;
  }
  if (threadIdx.x == 0) out[0] = cur[0];
}

static inline int imin2(int a, int b){ return a < b ? a : b; }

extern "C" void kernel_launch(void* const* d_in, const int* in_sizes, int n_in,
                              void* d_out, int out_size, void* d_ws, size_t ws_size,
                              hipStream_t stream){
  const float* tens = (const float*)d_in[0];
  const int*   samp = (const int*)d_in[1];
  float* out = (float*)d_out;
  float* ws  = (float*)d_ws;

  size_t off = 0;
  auto alloc = [&](size_t n){ float* p = ws + off; off += n; return p; };
  float* unit = alloc(64);
  float* mpo  = alloc((size_t)100 * 4096);
  float* bank[2][10];
  for (int b = 0; b < 2; ++b) for (int c = 0; c < 10; ++c) bank[b][c] = alloc(32768);
  float* renvB_[10]; float* lenvB_[10];
  for (int c = 0; c < 10; ++c) renvB_[c] = alloc(32768);
  for (int c = 0; c < 10; ++c) lenvB_[c] = alloc(32768);
  float* matbuf = alloc((size_t)512 * 512);
  float* carbuf[2] = { alloc(32768), alloc(32768) };
  float* optbuf = alloc(32768);

  k_init<<<dim3(1), dim3(1), 0, stream>>>(unit);
  k_mpo<<<dim3(100), dim3(256), 0, stream>>>(tens, samp, mpo);

  float* mps[10]; int mb[11];
  for (int c = 0; c < 10; ++c) mps[c] = unit;
  for (int c = 0; c <= 10; ++c) mb[c] = 1;
  int P = 1;

  int resL[10], resR[10];
  float* RENVP[10]; int renvDim[10];
  float* LENVP[10]; int lenvDim[10];

  for (int row = 0; row < 10; ++row){
    int Qd = (row == 9) ? 1 : 8;
    int Lm[10], Wm[10];
    for (int c = 0; c < 10; ++c){ Lm[c] = (c == 0) ? 1 : 8; Wm[c] = (c == 9) ? 1 : 8; }
    float** res_ = bank[row & 1];
    const float* mpoR = mpo + (size_t)row * 10 * 4096;

    // ---- init compressed MPS ----
    float* carry = unit; int kprev = 1; int cpar = 0;
    for (int c = 0; c < 10; ++c){
      int dmc = mb[c], rmc = mb[c + 1];
      int rows = kprev * Qd, cols = rmc * Wm[c];
      const float* wt = mpoR + (size_t)c * 4096;
      if (c == 9){
        k_init_theta<<<dim3(kprev), dim3(256), 0, stream>>>(carry, mps[c], wt, res_[9],
            kprev, dmc, Lm[c], P, rmc, Wm[c], Qd);
        resL[9] = kprev; resR[9] = cols;
      } else {
        k_init_theta<<<dim3(kprev), dim3(256), 0, stream>>>(carry, mps[c], wt, matbuf,
            kprev, dmc, Lm[c], P, rmc, Wm[c], Qd);
        int KK = imin2(64, imin2(rows, cols));
        k_panel<<<dim3(1), dim3(1024), 0, stream>>>(matbuf, res_[c], rows, KK, cols, 1, KK, 1);
        float* nc = carbuf[cpar]; cpar ^= 1;
        int tot = KK * cols;
        k_rmat<<<dim3((tot + 255) / 256), dim3(256), 0, stream>>>(res_[c], matbuf, nc,
            rows, KK, cols, cols, 1);
        resL[c] = kprev; resR[c] = KK;
        carry = nc; kprev = KK;
      }
    }

    // ---- build right envs ----
    RENVP[9] = unit; renvDim[9] = 1;
    for (int c = 8; c >= 0; --c){
      k_renv<<<dim3(resL[c + 1]), dim3(256), 0, stream>>>(res_[c + 1], RENVP[c + 1],
          mpoR + (size_t)(c + 1) * 4096, mps[c + 1], renvB_[c],
          resL[c + 1], Qd, resR[c + 1], mb[c + 2], Wm[c + 1], Lm[c + 1], P, mb[c + 1]);
      RENVP[c] = renvB_[c]; renvDim[c] = resL[c + 1];
    }

    for (int sweep = 0; sweep < 2; ++sweep){
      // ---- LR sweep ----
      LENVP[0] = unit; lenvDim[0] = 1;
      int aL = 1;
      for (int c = 0; c < 10; ++c){
        int bR = renvDim[c];
        const float* wt = mpoR + (size_t)c * 4096;
        float* outp = (c == 9) ? res_[9] : optbuf;
        k_optimal<<<dim3(aL), dim3(256), 0, stream>>>(mps[c], LENVP[c], wt, RENVP[c], outp,
            mb[c], P, mb[c + 1], Lm[c], aL, Wm[c], Qd, bR);
        if (c == 9){ resL[9] = aL; resR[9] = bR; break; }
        int rows = aL * Qd;
        int KK = imin2(64, imin2(rows, bR));
        k_panel<<<dim3(1), dim3(1024), 0, stream>>>(optbuf, res_[c], rows, KK, bR, 1, KK, 1);
        resL[c] = aL; resR[c] = KK;
        k_lenv<<<dim3(mb[c + 1]), dim3(256), 0, stream>>>(mps[c], LENVP[c], wt, res_[c],
            lenvB_[c + 1], mb[c], P, mb[c + 1], Lm[c], aL, Wm[c], Qd, KK);
        LENVP[c + 1] = lenvB_[c + 1]; lenvDim[c + 1] = KK;
        aL = KK;
      }
      // ---- RL sweep ----
      float* Rrun = unit; int bRr = 1;
      for (int c = 9; c >= 0; --c){
        RENVP[c] = Rrun; renvDim[c] = bRr;
        const float* wt = mpoR + (size_t)c * 4096;
        int aLc = lenvDim[c];
        float* outp = (c == 0) ? res_[0] : optbuf;
        k_optimal<<<dim3(aLc), dim3(256), 0, stream>>>(mps[c], LENVP[c], wt, Rrun, outp,
            mb[c], P, mb[c + 1], Lm[c], aLc, Wm[c], Qd, bRr);
        if (c == 0){ resL[0] = aLc; resR[0] = bRr; break; }
        int rowsT = Qd * bRr;
        int KK = imin2(64, imin2(rowsT, aLc));
        // panel on optimal^T: A_t(row=(q,b), col=a) at optbuf[col*rowsT + row]
        k_panel<<<dim3(1), dim3(1024), 0, stream>>>(optbuf, res_[c], rowsT, KK, 1, rowsT, 1, rowsT);
        resL[c] = KK; resR[c] = bRr;
        k_renv<<<dim3(KK), dim3(256), 0, stream>>>(res_[c], Rrun, wt, mps[c], renvB_[c - 1],
            KK, Qd, bRr, mb[c + 1], Wm[c], Lm[c], P, mb[c]);
        Rrun = renvB_[c - 1]; bRr = KK;
      }
    }

    // commit row result as new boundary
    for (int c = 0; c < 10; ++c){ mps[c] = res_[c]; mb[c + 1] = resR[c]; }
    mb[0] = 1;
    P = Qd;
  }

  FinalArgs fa;
  for (int c = 0; c < 10; ++c){ fa.t[c] = mps[c]; fa.dl[c] = resL[c]; fa.dr[c] = resR[c]; }
  k_final<<<dim3(1), dim3(64), 0, stream>>>(fa, out);
}